// Round 19
// baseline (249.561 us; speedup 1.0000x reference)
//
#include <hip/hip_runtime.h>
#include <hip/hip_bf16.h>

#define TAU_INV 2.0f
#define R_ 5
#define NU 50000
#define NM 20000
#define EDGES 100000
#define OUT_ 64

typedef __attribute__((ext_vector_type(8))) short short8;  // 8 bf16
typedef __attribute__((ext_vector_type(4))) float f32x4;

__device__ __forceinline__ float dot4(float4 a, float4 b) {
    return a.x * b.x + a.y * b.y + a.z * b.z + a.w * b.w;
}
__device__ __forceinline__ ushort f2bf(float x) {
    __hip_bfloat16 h = __float2bfloat16(x);
    return *reinterpret_cast<ushort*>(&h);
}
__device__ __forceinline__ uint pk2(float a, float b) {
    return (uint)f2bf(a) | ((uint)f2bf(b) << 16);
}
__device__ __forceinline__ float bf2f(ushort u) {
    uint v = ((uint)u) << 16;
    return *reinterpret_cast<float*>(&v);
}
__device__ __forceinline__ short8 pack8(float4 lo, float4 hi) {
    short8 v;
    v[0] = (short)f2bf(lo.x); v[1] = (short)f2bf(lo.y);
    v[2] = (short)f2bf(lo.z); v[3] = (short)f2bf(lo.w);
    v[4] = (short)f2bf(hi.x); v[5] = (short)f2bf(hi.y);
    v[6] = (short)f2bf(hi.z); v[7] = (short)f2bf(hi.w);
    return v;
}

// Gating + WAVE-PRIVATE MFMA message fusion (no __syncthreads, no cross-wave
// coupling). Each wave gates 16 edges in 4 rounds of the proven R12 4-edge
// structure, staging bf16 A-rows into its own LDS quadrant (R18's verified
// map). Then B-frags + 6 MFMAs + pre-wn msgP stream-out, all same-wave
// (compiler lgkmcnt handles LDS write->read).
__global__ __launch_bounds__(256) void k_edge_w(
    const float* __restrict__ ufk, const float* __restrict__ mfk,
    const float* __restrict__ ufs, const float* __restrict__ mfs,
    const float* __restrict__ rfeat, const float* __restrict__ proto,
    const float* __restrict__ eta, const int* __restrict__ eu,
    const int* __restrict__ em, const int* __restrict__ kp,
    const float* __restrict__ nwf, const float* __restrict__ rwf,
    const float* __restrict__ nwr, const float* __restrict__ rwr,
    float* __restrict__ wbuf, float* __restrict__ nrm_u, float* __restrict__ nrm_m,
    uint* __restrict__ msgP)
{
    __shared__ __align__(16) ushort s_a[4][16][104];   // 13.3 KB, wave-private quadrants

    const int tid = threadIdx.x;
    const int wv = tid >> 6, l = tid & 63;
    const int g16 = l >> 4;
    const int j   = l & 15;
    const int r = blockIdx.y;
    const int rE = r * EDGES;
    const int wbase = (blockIdx.x * 4 + wv) * 16;
    if (wbase >= EDGES) return;          // EDGES%16==0 -> waves fully live or dead
    const int kk = kp[0];
    char* awave = (char*)&s_a[wv][0][0];

#pragma unroll 1
    for (int s = 0; s < 4; ++s) {
        const int e = wbase + s * 4 + g16;
        const int idx = rE + e;
        const int u = eu[idx], m = em[idx];

        // ---- phase 1: gating weight (R12 math, verbatim) ----
        const float4 pu = ((const float4*)(ufs + (size_t)(r * NU + u) * 64))[j];
        const float4 pm = ((const float4*)(mfs + (size_t)(r * NM + m) * 64))[j];
        float p = dot4(pu, pm);
        p += __shfl_xor(p, 1); p += __shfl_xor(p, 2);
        const float es = expf(p * TAU_INV);
        float dsim = es;
        dsim += __shfl_xor(dsim, 4); dsim += __shfl_xor(dsim, 8);

        const int jc = j & 3;
        const float4 u4 = ((const float4*)(ufk + (size_t)(r * NU + u) * 16))[jc];
        const float4 m4 = ((const float4*)(mfk + (size_t)(r * NM + m) * 16))[jc];
        float su = dot4(u4, u4), sm = dot4(m4, m4), sd = dot4(u4, m4);
        su += __shfl_xor(su, 1); su += __shfl_xor(su, 2);
        sm += __shfl_xor(sm, 1); sm += __shfl_xor(sm, 2);
        sd += __shfl_xor(sd, 1); sd += __shfl_xor(sd, 2);
        const float nsim = expf(sd / (fmaxf(sqrtf(su), 1e-12f) * fmaxf(sqrtf(sm), 1e-12f)) * TAU_INV);

        const float4* rf4 = (const float4*)(rfeat + (size_t)idx * 256);
        const float4* pr4 = (const float4*)proto;
        const int base = (j >> 2) * 16 + (j & 3) * 4;
        const float4 rr0 = rf4[base + 0], rr1 = rf4[base + 1];
        const float4 rr2 = rf4[base + 2], rr3 = rf4[base + 3];
        float ap = dot4(rr0, pr4[base + 0]) + dot4(rr1, pr4[base + 1])
                 + dot4(rr2, pr4[base + 2]) + dot4(rr3, pr4[base + 3]);
        ap += __shfl_xor(ap, 1); ap += __shfl_xor(ap, 2);
        const float ea = expf(ap * TAU_INV);
        float dan = ea;
        dan += __shfl_xor(dan, 4); dan += __shfl_xor(dan, 8);
        const float adk = __shfl(ap, (l & 48) | (kk << 2));
        const float na = expf(adk * TAU_INV);

        const float gt = 1.0f / (1.0f + expf(-eta[idx]));
        const float w = gt * (na / dan) + (1.0f - gt) * (nsim / dsim);

        if (j == 0) {
            wbuf[idx] = w;
            atomicAdd(&nrm_u[u], w);
            atomicAdd(&nrm_m[m], w);
        }

        // ---- stage A row (R18's verified map; row = s*4+g16) ----
        char* arow = awave + (s * 4 + g16) * 208;
        if ((j >> 2) == kk) {                // this lane's rr0..3 = k-row chunk c
            const int c = j & 3;
            uint4 w0, w1;
            w0.x = pk2(rr0.x, rr0.y); w0.y = pk2(rr0.z, rr0.w);
            w0.z = pk2(rr1.x, rr1.y); w0.w = pk2(rr1.z, rr1.w);
            w1.x = pk2(rr2.x, rr2.y); w1.y = pk2(rr2.z, rr2.w);
            w1.z = pk2(rr3.x, rr3.y); w1.w = pk2(rr3.z, rr3.w);
            *(uint4*)(arow + c * 32)      = w0;
            *(uint4*)(arow + c * 32 + 16) = w1;
        }
        if (j < 4) {                         // ufk chunk jc=j -> k 64..79
            uint2 wd; wd.x = pk2(u4.x, u4.y); wd.y = pk2(u4.z, u4.w);
            *(uint2*)(arow + 128 + j * 8) = wd;
        } else if (j < 8) {                  // mfk chunk jc=j-4 -> k 80..95
            uint2 wd; wd.x = pk2(m4.x, m4.y); wd.y = pk2(m4.z, m4.w);
            *(uint2*)(arow + 160 + (j - 4) * 8) = wd;
        }
    }

    // ---- B-frags + MFMA + msgP stream-out (same wave; no barrier) ----
    {
        const int o = l & 15, q = l >> 4;
        short8 Bf[3], Br[3];
        const float* wfp = rwf + (size_t)r * 1024 + o * 64;
        const float* wrp = rwr + (size_t)r * 1024 + o * 64;
        const float* nfp = nwf + r * 256 + o * 16;
        const float* nrp = nwr + r * 256 + o * 16;
#pragma unroll
        for (int sl = 0; sl < 2; ++sl) {
            const int bk = 32 * sl + 8 * q;
            Bf[sl] = pack8(*(const float4*)(wfp + bk), *(const float4*)(wfp + bk + 4));
            Br[sl] = pack8(*(const float4*)(wrp + bk), *(const float4*)(wrp + bk + 4));
        }
        const short8 z8 = {0, 0, 0, 0, 0, 0, 0, 0};
        Bf[2] = (q < 2) ? pack8(*(const float4*)(nfp + 8 * q),
                                *(const float4*)(nfp + 8 * q + 4)) : z8;
        Br[2] = (q >= 2) ? pack8(*(const float4*)(nrp + 8 * (q - 2)),
                                 *(const float4*)(nrp + 8 * (q - 2) + 4)) : z8;

        f32x4 accm = {0.f, 0.f, 0.f, 0.f};
        f32x4 accu = {0.f, 0.f, 0.f, 0.f};
        const int row = l & 15;
#pragma unroll
        for (int sl = 0; sl < 3; ++sl) {
            const short8 a = *(const short8*)(awave + row * 208 + (sl * 32 + 8 * q) * 2);
            accm = __builtin_amdgcn_mfma_f32_16x16x32_bf16(a, Bf[sl], accm, 0, 0, 0);
            accu = __builtin_amdgcn_mfma_f32_16x16x32_bf16(a, Br[sl], accu, 0, 0, 0);
        }
#pragma unroll
        for (int i = 0; i < 4; ++i) {
            const int ej = q * 4 + i;        // D row = edge slot (m89 layout)
            msgP[((size_t)rE + wbase + ej) * 16 + o] = pk2(accm[i], accu[i]);
        }
    }
}

// R15-proven scatter: per edge read 64B packed pre-wn message, apply wn,
// two atomic RMWs. 8 edges per wave. (36 us measured)
__global__ __launch_bounds__(256) void k_scatter(
    const int* __restrict__ eu, const int* __restrict__ em,
    const float* __restrict__ wbuf, const float* __restrict__ nrm_u,
    const float* __restrict__ nrm_m, const uint* __restrict__ msg,
    float* __restrict__ upre, float* __restrict__ ipre, float* __restrict__ dist_out)
{
    const int tid = threadIdx.x;
    const int wv = tid >> 6, l = tid & 63;
    const int o = l & 15;
    const int r = blockIdx.y;
    const int rE = r * EDGES;
    const int ebase = (blockIdx.x * 4 + wv) * 8;   // EDGES = 3125*32 exact

    float wnsave = 0.f;
#pragma unroll
    for (int j = 0; j < 8; j += 2) {
        const int e0 = ebase + j, e1 = e0 + 1;
        const int u0 = eu[rE + e0], m0 = em[rE + e0];
        const int u1 = eu[rE + e1], m1 = em[rE + e1];
        const float wn0 = wbuf[rE + e0] / sqrtf(nrm_u[u0] * nrm_m[m0]);
        const float wn1 = wbuf[rE + e1] / sqrtf(nrm_u[u1] * nrm_m[m1]);
        if (l == j)     wnsave = wn0;
        if (l == j + 1) wnsave = wn1;

        const int  half = l >> 5;
        const int  eh   = half ? e1 : e0;
        const uint pk   = msg[(size_t)(rE + eh) * 16 + o];
        const float wnh = half ? wn1 : wn0;
        const bool up   = (l & 31) >= 16;
        const float val = bf2f(up ? (ushort)(pk >> 16) : (ushort)(pk & 0xffff)) * wnh;
        const int  uh   = half ? u1 : u0;
        const int  mh   = half ? m1 : m0;
        float* basep = up ? &upre[(size_t)uh * 16 + o] : &ipre[(size_t)mh * 16 + o];
        atomicAdd(basep, val);
    }
    if (l < 8)
        dist_out[rE + ebase + l] = wnsave;
}

// Fused leaky-relu + (N,16) x (16,64) FC for both tables. (unchanged)
__global__ __launch_bounds__(256) void k_fc(
    const float* __restrict__ upre, const float* __restrict__ ipre,
    const float* __restrict__ uw, const float* __restrict__ ub,
    const float* __restrict__ iw, const float* __restrict__ ib,
    float* __restrict__ out_u, float* __restrict__ out_i)
{
    const int tid = threadIdx.x;
    const int n = blockIdx.x * 4 + (tid >> 6);
    if (n >= NU + NM) return;
    const int o = tid & 63;
    const float* pre; const float* W; const float* B; float* dst;
    if (n < NU) { pre = upre + (size_t)n * 16; W = uw; B = ub; dst = out_u + (size_t)n * 64; }
    else { int n2 = n - NU; pre = ipre + (size_t)n2 * 16; W = iw; B = ib; dst = out_i + (size_t)n2 * 64; }
    float acc = B[o];
#pragma unroll
    for (int d = 0; d < 16; d++) {
        float x = pre[d];
        x = x >= 0.f ? x : 0.1f * x;
        acc += x * W[o * 16 + d];
    }
    dst[o] = acc;
}

extern "C" void kernel_launch(void* const* d_in, const int* in_sizes, int n_in,
                              void* d_out, int out_size, void* d_ws, size_t ws_size,
                              hipStream_t stream) {
    const float* ufk  = (const float*)d_in[0];
    const float* mfk  = (const float*)d_in[1];
    const float* ufs  = (const float*)d_in[2];
    const float* mfs  = (const float*)d_in[3];
    const float* rfe  = (const float*)d_in[4];
    const float* pro  = (const float*)d_in[5];
    const float* eta  = (const float*)d_in[6];
    const float* nwf  = (const float*)d_in[7];
    const float* rwf  = (const float*)d_in[8];
    const float* nwr  = (const float*)d_in[9];
    const float* rwr  = (const float*)d_in[10];
    const float* uw   = (const float*)d_in[11];
    const float* ub   = (const float*)d_in[12];
    const float* iw   = (const float*)d_in[13];
    const float* ib   = (const float*)d_in[14];
    const int*   eu   = (const int*)d_in[15];
    const int*   em   = (const int*)d_in[16];
    const int*   kp   = (const int*)d_in[17];

    float* out    = (float*)d_out;
    float* out_u  = out;                         // NU*64
    float* out_i  = out + (size_t)NU * 64;       // NM*64
    float* out_d  = out_i + (size_t)NM * 64;     // R*E

    float* ws    = (float*)d_ws;
    float* nrm_u = ws;                           // NU
    float* nrm_m = nrm_u + NU;                   // NM
    float* upre  = nrm_m + NM;                   // NU*16
    float* ipre  = upre + (size_t)NU * 16;       // NM*16
    float* wbuf  = ipre + (size_t)NM * 16;       // R*E
    uint*  msgP  = (uint*)(wbuf + (size_t)R_ * EDGES);  // R*E*16 uints = 32 MB (proven)

    const size_t zeroN = (size_t)NU + NM + (size_t)NU * 16 + (size_t)NM * 16;
    hipMemsetAsync(d_ws, 0, zeroN * sizeof(float), stream);

    dim3 gW((EDGES + 63) / 64, R_);   // 4 waves/block x 16 edges/wave
    k_edge_w<<<gW, 256, 0, stream>>>(ufk, mfk, ufs, mfs, rfe, pro, eta, eu, em, kp,
                                     nwf, rwf, nwr, rwr, wbuf, nrm_u, nrm_m, msgP);
    dim3 gS(EDGES / 32, R_);
    k_scatter<<<gS, 256, 0, stream>>>(eu, em, wbuf, nrm_u, nrm_m, msgP,
                                      upre, ipre, out_d);
    k_fc<<<((NU + NM) + 3) / 4, 256, 0, stream>>>(upre, ipre, uw, ub, iw, ib, out_u, out_i);
}

// Round 20
// 245.771 us; speedup vs baseline: 1.0154x; 1.0154x over previous
//
#include <hip/hip_runtime.h>
#include <hip/hip_bf16.h>

#define TAU_INV 2.0f
#define R_ 5
#define NU 50000
#define NM 20000
#define EDGES 100000
#define OUT_ 64

typedef __attribute__((ext_vector_type(8))) short short8;  // 8 bf16
typedef __attribute__((ext_vector_type(4))) float f32x4;
typedef __attribute__((address_space(3))) uint  lds_uint;
typedef const __attribute__((address_space(1))) uint g_uint;

__device__ __forceinline__ float dot4(float4 a, float4 b) {
    return a.x * b.x + a.y * b.y + a.z * b.z + a.w * b.w;
}
__device__ __forceinline__ ushort f2bf(float x) {
    __hip_bfloat16 h = __float2bfloat16(x);
    return *reinterpret_cast<ushort*>(&h);
}
__device__ __forceinline__ uint pk2(float a, float b) {
    return (uint)f2bf(a) | ((uint)f2bf(b) << 16);
}
__device__ __forceinline__ short8 pack8(float4 lo, float4 hi) {
    short8 v;
    v[0] = (short)f2bf(lo.x); v[1] = (short)f2bf(lo.y);
    v[2] = (short)f2bf(lo.z); v[3] = (short)f2bf(lo.w);
    v[4] = (short)f2bf(hi.x); v[5] = (short)f2bf(hi.y);
    v[6] = (short)f2bf(hi.z); v[7] = (short)f2bf(hi.w);
    return v;
}

// Gating kernel — R12/R14 proven form (118 us). 4 edges/wave, 16 lanes/edge.
__global__ __launch_bounds__(256) void k_edge_w(
    const float* __restrict__ ufk, const float* __restrict__ mfk,
    const float* __restrict__ ufs, const float* __restrict__ mfs,
    const float* __restrict__ rfeat, const float* __restrict__ proto,
    const float* __restrict__ eta, const int* __restrict__ eu,
    const int* __restrict__ em, const int* __restrict__ kp,
    float* __restrict__ wbuf, float* __restrict__ nrm_u, float* __restrict__ nrm_m)
{
    const int tid = threadIdx.x;
    const int wv = tid >> 6, l = tid & 63;
    const int g16 = l >> 4;
    const int j   = l & 15;
    const int r = blockIdx.y;
    const int e = (blockIdx.x * 4 + wv) * 4 + g16;   // 6250*16 = 100000 exact
    const int idx = r * EDGES + e;
    const int u = eu[idx], m = em[idx];
    const int kk = kp[0];

    const float4 pu = ((const float4*)(ufs + (size_t)(r * NU + u) * 64))[j];
    const float4 pm = ((const float4*)(mfs + (size_t)(r * NM + m) * 64))[j];
    float p = dot4(pu, pm);
    p += __shfl_xor(p, 1); p += __shfl_xor(p, 2);
    const float es = expf(p * TAU_INV);
    float dsim = es;
    dsim += __shfl_xor(dsim, 4); dsim += __shfl_xor(dsim, 8);

    const int jc = j & 3;
    const float4 u4 = ((const float4*)(ufk + (size_t)(r * NU + u) * 16))[jc];
    const float4 m4 = ((const float4*)(mfk + (size_t)(r * NM + m) * 16))[jc];
    float su = dot4(u4, u4), sm = dot4(m4, m4), sd = dot4(u4, m4);
    su += __shfl_xor(su, 1); su += __shfl_xor(su, 2);
    sm += __shfl_xor(sm, 1); sm += __shfl_xor(sm, 2);
    sd += __shfl_xor(sd, 1); sd += __shfl_xor(sd, 2);
    const float nsim = expf(sd / (fmaxf(sqrtf(su), 1e-12f) * fmaxf(sqrtf(sm), 1e-12f)) * TAU_INV);

    const float4* rf4 = (const float4*)(rfeat + (size_t)idx * 256);
    const float4* pr4 = (const float4*)proto;
    const int base = (j >> 2) * 16 + (j & 3) * 4;
    float ap = 0.f;
#pragma unroll
    for (int t = 0; t < 4; ++t)
        ap += dot4(rf4[base + t], pr4[base + t]);
    ap += __shfl_xor(ap, 1); ap += __shfl_xor(ap, 2);
    const float ea = expf(ap * TAU_INV);
    float dan = ea;
    dan += __shfl_xor(dan, 4); dan += __shfl_xor(dan, 8);
    const float adk = __shfl(ap, (l & 48) | (kk << 2));
    const float na = expf(adk * TAU_INV);

    const float gt = 1.0f / (1.0f + expf(-eta[idx]));
    const float w = gt * (na / dan) + (1.0f - gt) * (nsim / dsim);

    if (j == 0) {
        wbuf[idx] = w;
        atomicAdd(&nrm_u[u], w);
        atomicAdd(&nrm_m[m], w);
    }
}

// MFMA msg kernel, EPW=16, DMA staging:
//  - rfeat k-rows: 5x global_load_lds width=16 -> f32 LDS, 272B-padded rows
//    (slot s -> row s/17, part s%17), zero dest VGPRs, zero cvt VALU.
//  - ufk/mfk gathers: st[2] reg-stage -> bf16 LDS rows (80B stride).
//  - A-frag: slices 0-1 = 2x ds_read_b128(f32)+pack8; slice 2 = ds_read_b128(bf16).
//  - one vmcnt(0) fence before frag reads; wave-private LDS, no barrier.
__global__ __launch_bounds__(256) void k_edge_msg(
    const float* __restrict__ ufk, const float* __restrict__ mfk,
    const float* __restrict__ rfeat,
    const float* __restrict__ nwf, const float* __restrict__ rwf,
    const float* __restrict__ nwr, const float* __restrict__ rwr,
    const int* __restrict__ eu, const int* __restrict__ em, const int* __restrict__ kp,
    const float* __restrict__ wbuf, const float* __restrict__ nrm_u,
    const float* __restrict__ nrm_m,
    float* __restrict__ upre, float* __restrict__ ipre, float* __restrict__ dist_out)
{
    __shared__ __align__(16) float  s_rf[4][1280];   // 5120B/wave: 320 f4 slots (16 rows x 272B + slack)
    __shared__ __align__(16) ushort s_nd[4][640];    // 1280B/wave: 16 rows x 80B

    const int tid = threadIdx.x;
    const int wv = tid >> 6, l = tid & 63;
    const int o = l & 15, q = l >> 4;
    const int r = blockIdx.y;
    const int kk = kp[0];
    const int rE = r * EDGES;
    const int ebase = (blockIdx.x * 4 + wv) * 16;
    if (ebase >= EDGES) return;                      // EDGES%16==0: waves fully live/dead

    // ---- B fragments (R14 verbatim): B[k][o], k = 32*sl + 8*q + {0..7} ----
    short8 Bf[3], Br[3];
    {
        const float* wfp = rwf + (size_t)r * 1024 + o * 64;
        const float* wrp = rwr + (size_t)r * 1024 + o * 64;
        const float* nfp = nwf + r * 256 + o * 16;
        const float* nrp = nwr + r * 256 + o * 16;
#pragma unroll
        for (int sl = 0; sl < 2; ++sl) {
            const int bk = 32 * sl + 8 * q;
            Bf[sl] = pack8(*(const float4*)(wfp + bk), *(const float4*)(wfp + bk + 4));
            Br[sl] = pack8(*(const float4*)(wrp + bk), *(const float4*)(wrp + bk + 4));
        }
        const short8 z8 = {0, 0, 0, 0, 0, 0, 0, 0};
        Bf[2] = (q < 2) ? pack8(*(const float4*)(nfp + 8 * q),
                                *(const float4*)(nfp + 8 * q + 4)) : z8;
        Br[2] = (q >= 2) ? pack8(*(const float4*)(nrp + 8 * (q - 2)),
                                 *(const float4*)(nrp + 8 * (q - 2) + 4)) : z8;
    }

    // ---- header: lane (l&15)=j holds edge ebase+j ----
    int eu16, em16; float wn16;
    {
        const int e2 = ebase + o;
        eu16 = eu[rE + e2]; em16 = em[rE + e2];
        wn16 = wbuf[rE + e2] / sqrtf(nrm_u[eu16] * nrm_m[em16]);
    }
    if (l < 16)
        dist_out[rE + ebase + l] = wn16;             // coalesced 64B store per wave

    // ---- rf k-rows via global_load_lds (async DMA, no VGPR round-trip) ----
    float* rfw = &s_rf[wv][0];
#pragma unroll
    for (int t = 0; t < 5; ++t) {
        const int s = t * 64 + l;                    // slot 0..319
        int jj = s / 17, pp = s % 17;
        if (jj > 15) { jj = 15; pp = 15; }           // tail slots -> harmless dup into slack
        if (pp > 15) pp = 15;                        // row pad slot -> dup of part 15
        const float* gp = rfeat + ((size_t)(rE + ebase + jj) * 4 + kk) * 64 + pp * 4;
        __builtin_amdgcn_global_load_lds((g_uint*)gp, (lds_uint*)(rfw + t * 256), 16, 0, 0);
    }

    // ---- node rows: reg-stage + bf16 pack (st[2] only) ----
    float4 st[2];
#pragma unroll
    for (int t = 0; t < 2; ++t) {
        const int s = t * 64 + l;                    // 0..127
        const int jj = s >> 3, pp = s & 7;
        const int uj = __shfl(eu16, jj);             // full convergence
        const int mj = __shfl(em16, jj);
        const float4* src = (pp < 4)
            ? (const float4*)(ufk + (size_t)(r * NU + uj) * 16) + pp
            : (const float4*)(mfk + (size_t)(r * NM + mj) * 16) + (pp - 4);
        st[t] = *src;
    }
    char* ndw = (char*)&s_nd[wv][0];
#pragma unroll
    for (int t = 0; t < 2; ++t) {
        const int s = t * 64 + l;
        const int jj = s >> 3, pp = s & 7;
        uint2 wd; wd.x = pk2(st[t].x, st[t].y); wd.y = pk2(st[t].z, st[t].w);
        *(uint2*)(ndw + jj * 80 + pp * 8) = wd;
    }

    asm volatile("s_waitcnt vmcnt(0)" ::: "memory"); // drain DMA before LDS reads
    __builtin_amdgcn_sched_barrier(0);

    // ---- MFMA: A row = edge slot o, k-chunk 8q per slice ----
    f32x4 accm = {0.f, 0.f, 0.f, 0.f};
    f32x4 accu = {0.f, 0.f, 0.f, 0.f};
    const char* rrow = (const char*)rfw + o * 272;
#pragma unroll
    for (int sl = 0; sl < 2; ++sl) {
        const float4* L4 = (const float4*)(rrow + sl * 128 + q * 32);
        const short8 a = pack8(L4[0], L4[1]);
        accm = __builtin_amdgcn_mfma_f32_16x16x32_bf16(a, Bf[sl], accm, 0, 0, 0);
        accu = __builtin_amdgcn_mfma_f32_16x16x32_bf16(a, Br[sl], accu, 0, 0, 0);
    }
    {
        const short8 a = *(const short8*)(ndw + o * 80 + q * 16);
        accm = __builtin_amdgcn_mfma_f32_16x16x32_bf16(a, Bf[2], accm, 0, 0, 0);
        accu = __builtin_amdgcn_mfma_f32_16x16x32_bf16(a, Br[2], accu, 0, 0, 0);
    }

    // ---- scatter: D col = o, row = q*4+i = edge slot (m89 layout) ----
#pragma unroll
    for (int i = 0; i < 4; ++i) {
        const int jj = q * 4 + i;
        const float wnj = __shfl(wn16, jj);
        const int   uj  = __shfl(eu16, jj);
        const int   mj  = __shfl(em16, jj);
        atomicAdd(&ipre[(size_t)mj * 16 + o], accm[i] * wnj);
        atomicAdd(&upre[(size_t)uj * 16 + o], accu[i] * wnj);
    }
}

// Fused leaky-relu + (N,16) x (16,64) FC for both tables. (unchanged)
__global__ __launch_bounds__(256) void k_fc(
    const float* __restrict__ upre, const float* __restrict__ ipre,
    const float* __restrict__ uw, const float* __restrict__ ub,
    const float* __restrict__ iw, const float* __restrict__ ib,
    float* __restrict__ out_u, float* __restrict__ out_i)
{
    const int tid = threadIdx.x;
    const int n = blockIdx.x * 4 + (tid >> 6);
    if (n >= NU + NM) return;
    const int o = tid & 63;
    const float* pre; const float* W; const float* B; float* dst;
    if (n < NU) { pre = upre + (size_t)n * 16; W = uw; B = ub; dst = out_u + (size_t)n * 64; }
    else { int n2 = n - NU; pre = ipre + (size_t)n2 * 16; W = iw; B = ib; dst = out_i + (size_t)n2 * 64; }
    float acc = B[o];
#pragma unroll
    for (int d = 0; d < 16; d++) {
        float x = pre[d];
        x = x >= 0.f ? x : 0.1f * x;
        acc += x * W[o * 16 + d];
    }
    dst[o] = acc;
}

extern "C" void kernel_launch(void* const* d_in, const int* in_sizes, int n_in,
                              void* d_out, int out_size, void* d_ws, size_t ws_size,
                              hipStream_t stream) {
    const float* ufk  = (const float*)d_in[0];
    const float* mfk  = (const float*)d_in[1];
    const float* ufs  = (const float*)d_in[2];
    const float* mfs  = (const float*)d_in[3];
    const float* rfe  = (const float*)d_in[4];
    const float* pro  = (const float*)d_in[5];
    const float* eta  = (const float*)d_in[6];
    const float* nwf  = (const float*)d_in[7];
    const float* rwf  = (const float*)d_in[8];
    const float* nwr  = (const float*)d_in[9];
    const float* rwr  = (const float*)d_in[10];
    const float* uw   = (const float*)d_in[11];
    const float* ub   = (const float*)d_in[12];
    const float* iw   = (const float*)d_in[13];
    const float* ib   = (const float*)d_in[14];
    const int*   eu   = (const int*)d_in[15];
    const int*   em   = (const int*)d_in[16];
    const int*   kp   = (const int*)d_in[17];

    float* out    = (float*)d_out;
    float* out_u  = out;                         // NU*64
    float* out_i  = out + (size_t)NU * 64;       // NM*64
    float* out_d  = out_i + (size_t)NM * 64;     // R*E

    float* ws    = (float*)d_ws;
    float* nrm_u = ws;                           // NU
    float* nrm_m = nrm_u + NU;                   // NM
    float* upre  = nrm_m + NM;                   // NU*16
    float* ipre  = upre + (size_t)NU * 16;       // NM*16
    float* wbuf  = ipre + (size_t)NM * 16;       // R*E

    const size_t zeroN = (size_t)NU + NM + (size_t)NU * 16 + (size_t)NM * 16;
    hipMemsetAsync(d_ws, 0, zeroN * sizeof(float), stream);

    dim3 gW((EDGES + 15) / 16, R_);
    k_edge_w<<<gW, 256, 0, stream>>>(ufk, mfk, ufs, mfs, rfe, pro, eta, eu, em, kp,
                                     wbuf, nrm_u, nrm_m);
    dim3 gM((EDGES + 63) / 64, R_);   // 4 waves/block x 16 edges/wave
    k_edge_msg<<<gM, 256, 0, stream>>>(ufk, mfk, rfe, nwf, rwf, nwr, rwr, eu, em, kp,
                                       wbuf, nrm_u, nrm_m, upre, ipre, out_d);
    k_fc<<<((NU + NM) + 3) / 4, 256, 0, stream>>>(upre, ipre, uw, ub, iw, ib, out_u, out_i);
}

// Round 21
// 245.698 us; speedup vs baseline: 1.0157x; 1.0003x over previous
//
#include <hip/hip_runtime.h>
#include <hip/hip_bf16.h>

#define TAU_INV 2.0f
#define R_ 5
#define NU 50000
#define NM 20000
#define EDGES 100000
#define F_ 4
#define D_ 16
#define DR 64
#define OUT_ 64
#define EPW 32  // edges per wave in k_edge_msg (2 MFMA 16-blocks)

typedef __attribute__((ext_vector_type(8))) short short8;  // 8 bf16
typedef __attribute__((ext_vector_type(4))) float f32x4;

__device__ __forceinline__ float dot4(float4 a, float4 b) {
    return a.x * b.x + a.y * b.y + a.z * b.z + a.w * b.w;
}

__device__ __forceinline__ ushort f2bf(float x) {
    __hip_bfloat16 h = __float2bfloat16(x);
    return *reinterpret_cast<ushort*>(&h);
}

__device__ __forceinline__ short8 pack8(float4 lo, float4 hi) {
    short8 v;
    v[0] = (short)f2bf(lo.x); v[1] = (short)f2bf(lo.y);
    v[2] = (short)f2bf(lo.z); v[3] = (short)f2bf(lo.w);
    v[4] = (short)f2bf(hi.x); v[5] = (short)f2bf(hi.y);
    v[6] = (short)f2bf(hi.z); v[7] = (short)f2bf(hi.w);
    return v;
}

// 4 edges per wave, 16 lanes per edge. ~4 shfl/edge, float4 loads. (R12 proven)
__global__ __launch_bounds__(256) void k_edge_w(
    const float* __restrict__ ufk, const float* __restrict__ mfk,
    const float* __restrict__ ufs, const float* __restrict__ mfs,
    const float* __restrict__ rfeat, const float* __restrict__ proto,
    const float* __restrict__ eta, const int* __restrict__ eu,
    const int* __restrict__ em, const int* __restrict__ kp,
    float* __restrict__ wbuf, float* __restrict__ nrm_u, float* __restrict__ nrm_m)
{
    const int tid = threadIdx.x;
    const int wv = tid >> 6, l = tid & 63;
    const int g16 = l >> 4;
    const int j   = l & 15;
    const int r = blockIdx.y;
    int e = (blockIdx.x * 4 + wv) * 4 + g16;
    const bool live = (e < EDGES);
    if (e >= EDGES) e = EDGES - 1;
    const int idx = r * EDGES + e;
    const int u = eu[idx], m = em[idx];
    const int kk = kp[0];

    const float4 pu = ((const float4*)(ufs + (size_t)(r * NU + u) * 64))[j];
    const float4 pm = ((const float4*)(mfs + (size_t)(r * NM + m) * 64))[j];
    float p = dot4(pu, pm);
    p += __shfl_xor(p, 1); p += __shfl_xor(p, 2);
    const float es = expf(p * TAU_INV);
    float dsim = es;
    dsim += __shfl_xor(dsim, 4); dsim += __shfl_xor(dsim, 8);

    const int jc = j & 3;
    const float4 u4 = ((const float4*)(ufk + (size_t)(r * NU + u) * 16))[jc];
    const float4 m4 = ((const float4*)(mfk + (size_t)(r * NM + m) * 16))[jc];
    float su = dot4(u4, u4), sm = dot4(m4, m4), sd = dot4(u4, m4);
    su += __shfl_xor(su, 1); su += __shfl_xor(su, 2);
    sm += __shfl_xor(sm, 1); sm += __shfl_xor(sm, 2);
    sd += __shfl_xor(sd, 1); sd += __shfl_xor(sd, 2);
    const float nsim = expf(sd / (fmaxf(sqrtf(su), 1e-12f) * fmaxf(sqrtf(sm), 1e-12f)) * TAU_INV);

    const float4* rf4 = (const float4*)(rfeat + (size_t)idx * 256);
    const float4* pr4 = (const float4*)proto;
    const int base = (j >> 2) * 16 + (j & 3) * 4;
    float ap = 0.f;
#pragma unroll
    for (int t = 0; t < 4; ++t)
        ap += dot4(rf4[base + t], pr4[base + t]);
    ap += __shfl_xor(ap, 1); ap += __shfl_xor(ap, 2);
    const float ea = expf(ap * TAU_INV);
    float dan = ea;
    dan += __shfl_xor(dan, 4); dan += __shfl_xor(dan, 8);
    const float adk = __shfl(ap, (l & 48) | (kk << 2));
    const float na = expf(adk * TAU_INV);

    const float gt = 1.0f / (1.0f + expf(-eta[idx]));
    const float w = gt * (na / dan) + (1.0f - gt) * (nsim / dsim);

    if (live && j == 0) {
        wbuf[idx] = w;
        atomicAdd(&nrm_u[u], w);
        atomicAdd(&nrm_m[m], w);
    }
}

// MFMA msg kernel (R14, best measured). Per wave: 32 edges. A = [rf|ufk|mfk]
// bf16 in LDS (104-ushort padded rows); B_f/B_r register fragments shared
// across the two MFMAs; f32 accumulate; paired atomic scatter.
__global__ __launch_bounds__(256) void k_edge_msg(
    const float* __restrict__ ufk, const float* __restrict__ mfk,
    const float* __restrict__ rfeat,
    const float* __restrict__ nwf, const float* __restrict__ rwf,
    const float* __restrict__ nwr, const float* __restrict__ rwr,
    const int* __restrict__ eu, const int* __restrict__ em, const int* __restrict__ kp,
    const float* __restrict__ wbuf, const float* __restrict__ nrm_u,
    const float* __restrict__ nrm_m,
    float* __restrict__ upre, float* __restrict__ ipre, float* __restrict__ dist_out)
{
    __shared__ __align__(16) ushort s_a[4][EPW][104];

    const int tid = threadIdx.x;
    const int wv = tid >> 6, l = tid & 63;
    const int o = l & 15, q = l >> 4;
    const int r = blockIdx.y;
    const int kk = kp[0];
    const int rE = r * EDGES;

    short8 Bf[3], Br[3];
    {
        const float* wfp = rwf + (size_t)r * 1024 + o * 64;
        const float* wrp = rwr + (size_t)r * 1024 + o * 64;
        const float* nfp = nwf + r * 256 + o * 16;
        const float* nrp = nwr + r * 256 + o * 16;
#pragma unroll
        for (int sl = 0; sl < 2; ++sl) {
            const int bk = 32 * sl + 8 * q;
            Bf[sl] = pack8(*(const float4*)(wfp + bk), *(const float4*)(wfp + bk + 4));
            Br[sl] = pack8(*(const float4*)(wrp + bk), *(const float4*)(wrp + bk + 4));
        }
        const short8 z8 = {0, 0, 0, 0, 0, 0, 0, 0};
        Bf[2] = (q < 2) ? pack8(*(const float4*)(nfp + 8 * q),
                                *(const float4*)(nfp + 8 * q + 4)) : z8;
        Br[2] = (q >= 2) ? pack8(*(const float4*)(nrp + 8 * (q - 2)),
                                 *(const float4*)(nrp + 8 * (q - 2) + 4)) : z8;
    }

    const int ebase = (blockIdx.x * 4 + wv) * EPW;

    int eu32, em32; float wn32;
    {
        int e2 = ebase + (l & 31); if (e2 >= EDGES) e2 = EDGES - 1;
        eu32 = eu[rE + e2]; em32 = em[rE + e2];
        const float w0 = wbuf[rE + e2];
        wn32 = w0 / sqrtf(nrm_u[eu32] * nrm_m[em32]);
    }
    if (l < 32 && ebase + l < EDGES)
        dist_out[rE + ebase + l] = wn32;

    float4 st[12];
#pragma unroll
    for (int t = 0; t < 12; ++t) {
        const int s = l + 64 * t;
        const int j = s / 24;
        const int p = s % 24;
        int e2 = ebase + j; if (e2 >= EDGES) e2 = EDGES - 1;
        const int uj = __shfl(eu32, j);   // full convergence
        const int mj = __shfl(em32, j);
        const float4* src;
        if (p < 16)      src = (const float4*)(rfeat + ((size_t)(rE + e2) * 4 + kk) * 64) + p;
        else if (p < 20) src = (const float4*)(ufk + (size_t)(r * NU + uj) * 16) + (p - 16);
        else             src = (const float4*)(mfk + (size_t)(r * NM + mj) * 16) + (p - 20);
        st[t] = *src;
    }
    char* abase = (char*)&s_a[wv][0][0];
#pragma unroll
    for (int t = 0; t < 12; ++t) {
        const int s = l + 64 * t;
        const int j = s / 24;
        const int p = s % 24;
        uint2 wds;
        wds.x = (uint)f2bf(st[t].x) | ((uint)f2bf(st[t].y) << 16);
        wds.y = (uint)f2bf(st[t].z) | ((uint)f2bf(st[t].w) << 16);
        *(uint2*)(abase + j * 208 + p * 8) = wds;
    }

#pragma unroll
    for (int g = 0; g < 2; ++g) {
        f32x4 accm = {0.f, 0.f, 0.f, 0.f};
        f32x4 accu = {0.f, 0.f, 0.f, 0.f};
        const int row = g * 16 + o;
#pragma unroll
        for (int sl = 0; sl < 3; ++sl) {
            const short8 a = *(const short8*)(abase + row * 208 + (sl * 32 + 8 * q) * 2);
            accm = __builtin_amdgcn_mfma_f32_16x16x32_bf16(a, Bf[sl], accm, 0, 0, 0);
            accu = __builtin_amdgcn_mfma_f32_16x16x32_bf16(a, Br[sl], accu, 0, 0, 0);
        }
#pragma unroll
        for (int i = 0; i < 4; ++i) {
            const int j = g * 16 + q * 4 + i;
            const float wnj = __shfl(wn32, j);
            const int   uj  = __shfl(eu32, j);
            const int   mj  = __shfl(em32, j);
            const bool  livej = (ebase + j) < EDGES;
            const float vm = accm[i] * wnj;
            const float vu = accu[i] * wnj;
            if (livej) {
                atomicAdd(&ipre[(size_t)mj * 16 + o], vm);
                atomicAdd(&upre[(size_t)uj * 16 + o], vu);
            }
        }
    }
}

// Fused leaky-relu + (N,16) x (16,64) FC for both tables.
__global__ __launch_bounds__(256) void k_fc(
    const float* __restrict__ upre, const float* __restrict__ ipre,
    const float* __restrict__ uw, const float* __restrict__ ub,
    const float* __restrict__ iw, const float* __restrict__ ib,
    float* __restrict__ out_u, float* __restrict__ out_i)
{
    const int tid = threadIdx.x;
    const int n = blockIdx.x * 4 + (tid >> 6);
    if (n >= NU + NM) return;
    const int o = tid & 63;
    const float* pre; const float* W; const float* B; float* dst;
    if (n < NU) { pre = upre + (size_t)n * 16; W = uw; B = ub; dst = out_u + (size_t)n * 64; }
    else { int n2 = n - NU; pre = ipre + (size_t)n2 * 16; W = iw; B = ib; dst = out_i + (size_t)n2 * 64; }
    float acc = B[o];
#pragma unroll
    for (int d = 0; d < 16; d++) {
        float x = pre[d];
        x = x >= 0.f ? x : 0.1f * x;
        acc += x * W[o * 16 + d];
    }
    dst[o] = acc;
}

extern "C" void kernel_launch(void* const* d_in, const int* in_sizes, int n_in,
                              void* d_out, int out_size, void* d_ws, size_t ws_size,
                              hipStream_t stream) {
    const float* ufk  = (const float*)d_in[0];
    const float* mfk  = (const float*)d_in[1];
    const float* ufs  = (const float*)d_in[2];
    const float* mfs  = (const float*)d_in[3];
    const float* rfe  = (const float*)d_in[4];
    const float* pro  = (const float*)d_in[5];
    const float* eta  = (const float*)d_in[6];
    const float* nwf  = (const float*)d_in[7];
    const float* rwf  = (const float*)d_in[8];
    const float* nwr  = (const float*)d_in[9];
    const float* rwr  = (const float*)d_in[10];
    const float* uw   = (const float*)d_in[11];
    const float* ub   = (const float*)d_in[12];
    const float* iw   = (const float*)d_in[13];
    const float* ib   = (const float*)d_in[14];
    const int*   eu   = (const int*)d_in[15];
    const int*   em   = (const int*)d_in[16];
    const int*   kp   = (const int*)d_in[17];

    float* out    = (float*)d_out;
    float* out_u  = out;                         // NU*64
    float* out_i  = out + (size_t)NU * 64;       // NM*64
    float* out_d  = out_i + (size_t)NM * 64;     // R*E

    float* ws    = (float*)d_ws;
    float* nrm_u = ws;                           // NU
    float* nrm_m = nrm_u + NU;                   // NM
    float* upre  = nrm_m + NM;                   // NU*16
    float* ipre  = upre + (size_t)NU * 16;       // NM*16
    float* wbuf  = ipre + (size_t)NM * 16;       // R*E

    const size_t zeroN = (size_t)NU + NM + (size_t)NU * 16 + (size_t)NM * 16;
    hipMemsetAsync(d_ws, 0, zeroN * sizeof(float), stream);

    dim3 gW((EDGES + 15) / 16, R_);
    k_edge_w<<<gW, 256, 0, stream>>>(ufk, mfk, ufs, mfs, rfe, pro, eta, eu, em, kp,
                                     wbuf, nrm_u, nrm_m);
    dim3 gM((EDGES + 4 * EPW - 1) / (4 * EPW), R_);
    k_edge_msg<<<gM, 256, 0, stream>>>(ufk, mfk, rfe, nwf, rwf, nwr, rwr, eu, em, kp,
                                       wbuf, nrm_u, nrm_m, upre, ipre, out_d);
    k_fc<<<((NU + NM) + 3) / 4, 256, 0, stream>>>(upre, ipre, uw, ub, iw, ib, out_u, out_i);
}